// Round 2
// 1397.799 us; speedup vs baseline: 1.2821x; 1.2821x over previous
//
#include <hip/hip_runtime.h>

// DistanceScaledDotAttention: B=4,H=8,S=2048,D=64
//   scores = (Q K^T / 8) * dist; masked -> -1e10; softmax; ctx = P V
//   outputs: ctx [4,8,2048,64] fp32, attn [4,8,2048,2048] fp32 (concat in d_out)
//
// v2 structure:
//   prep_kernel: K,V -> f16 MFMA-fragment planes in workspace (16 MiB).
//                Kf0/Kf1 = QK^T B-fragments, Vf0/Vf1 = PV B-fragments (pre-transposed).
//   dsda_kernel: one block = 8 q-rows of one (b,h); 32 k-tiles of 64.
//                No K/V LDS staging at all -> 1 barrier/tile instead of 3.
//                LDS = e_smem (8x2048 f16, XOR-swizzled: byte ^= row<<4) so the
//                PV ds_read_b128 A-fragment reads are bank-conflict-free.
//                dist/mask loads + attn stores are nontemporal (touch-once stream,
//                keeps fragment planes resident in L2).

typedef float v4f __attribute__((ext_vector_type(4)));
typedef _Float16 v8h __attribute__((ext_vector_type(8)));

#define SEQ 2048
#define DH  64
#define TQ  8
#define TK  64
#define NKT (SEQ / TK)   // 32
#define NBH 32
#define PLANE ((size_t)NBH * NKT * 256)   // v8h elements per fragment plane (4 MiB)

__device__ inline v8h cvt8(float4 a, float4 b) {
    v8h h;
    h[0] = (_Float16)a.x; h[1] = (_Float16)a.y; h[2] = (_Float16)a.z; h[3] = (_Float16)a.w;
    h[4] = (_Float16)b.x; h[5] = (_Float16)b.y; h[6] = (_Float16)b.z; h[7] = (_Float16)b.w;
    return h;
}

// ---- prep: build fragment planes --------------------------------------------
// Kf0[bh][kt][tid] = { (f16)K[bh][kt*64 + 16*wave + l16][quad*8 + j] , j=0..7 }
// Kf1: d += 32.
// Vf0[bh][kt][tid] = { (f16)V[bh][kt*64 + quad*8 + j][wave*16 + l16] , j=0..7 }
// Vf1: k += 32.
__global__ __launch_bounds__(256)
void prep_kernel(const float* __restrict__ Kg, const float* __restrict__ Vg,
                 v8h* __restrict__ W)
{
    const int kt   = blockIdx.x;
    const int bh   = blockIdx.y;
    const int tid  = (int)threadIdx.x;
    const int wave = tid >> 6;
    const int lane = tid & 63;
    const int quad = lane >> 4;
    const int l16  = lane & 15;
    const int k0   = kt * TK;

    const size_t bh_off = (size_t)bh * SEQ * DH;
    const size_t fi     = ((size_t)bh * NKT + kt) * 256 + tid;

    const float* kr = Kg + bh_off + (size_t)(k0 + wave * 16 + l16) * DH + quad * 8;
    W[fi]         = cvt8(((const float4*)kr)[0], ((const float4*)kr)[1]);
    W[PLANE + fi] = cvt8(((const float4*)(kr + 32))[0], ((const float4*)(kr + 32))[1]);

    const float* vc = Vg + bh_off + (size_t)(k0 + quad * 8) * DH + wave * 16 + l16;
    v8h v0, v1;
#pragma unroll
    for (int j = 0; j < 8; ++j) {
        v0[j] = (_Float16)vc[(size_t)j * DH];
        v1[j] = (_Float16)vc[(size_t)(j + 32) * DH];
    }
    W[2 * PLANE + fi] = v0;
    W[3 * PLANE + fi] = v1;
}

// ---- main -------------------------------------------------------------------
template<bool USE_WS>
__global__ __launch_bounds__(256, 4)
void dsda_kernel(const float* __restrict__ Qg, const float* __restrict__ Kg,
                 const float* __restrict__ Vg, const float* __restrict__ distg,
                 const int* __restrict__ maskg, const v8h* __restrict__ W,
                 float* __restrict__ ctx_out, float* __restrict__ attn_out)
{
    const int qt   = blockIdx.x;    // 0..255 (fast dim: same bh streams together -> L2 reuse of frags)
    const int bh   = blockIdx.y;    // 0..31
    const int q0   = qt * TQ;
    const int tid  = (int)threadIdx.x;
    const int wave = tid >> 6;
    const int lane = tid & 63;
    const int quad = lane >> 4;
    const int l16  = lane & 15;

    // e_smem: swizzled addressing, byte(row,col) = row*4096 + ((col*2) ^ (row<<4))
    __shared__ __align__(16) _Float16 e_smem[TQ * SEQ];   // 32 KB
    __shared__ float rs[TQ];
    if (tid < TQ) rs[tid] = 0.f;

    const size_t bh_off  = (size_t)bh * SEQ;
    const float* Qb = Qg + bh_off * DH;
    const float* Kb = Kg + bh_off * DH;
    const float* Vb = Vg + bh_off * DH;
    const size_t dm_base = (bh_off + (size_t)q0) * SEQ;

    // Q A-fragments (persist): A[m=l16][k = s*32 + quad*8 + j]
    v8h aq0 = {}, aq1 = {};
    if (l16 < TQ) {
        const float* qrow = Qb + (size_t)(q0 + l16) * DH;
        const float4* p0 = (const float4*)(qrow + quad * 8);
        const float4* p1 = (const float4*)(qrow + 32 + quad * 8);
        aq0 = cvt8(p0[0], p0[1]);
        aq1 = cvt8(p1[0], p1[1]);
    }

    v4f acc_pv = {0.f, 0.f, 0.f, 0.f};      // ctx acc: [row=quad*4+r][d=wave*16+l16]
    float rsum[4] = {0.f, 0.f, 0.f, 0.f};
    const size_t fbase = (size_t)bh * NKT * 256 + tid;

    for (int kt = 0; kt < NKT; ++kt) {
        const int k0 = kt * TK;

        // ---- K/V fragments: one coalesced 16B load each ----
        v8h bk0, bk1, bv0, bv1;
        if constexpr (USE_WS) {
            const size_t fi = fbase + (size_t)kt * 256;
            bk0 = W[fi];
            bk1 = W[PLANE + fi];
            bv0 = W[2 * PLANE + fi];
            bv1 = W[3 * PLANE + fi];
        } else {
            const float* kr = Kb + (size_t)(k0 + wave * 16 + l16) * DH + quad * 8;
            bk0 = cvt8(((const float4*)kr)[0], ((const float4*)kr)[1]);
            bk1 = cvt8(((const float4*)(kr + 32))[0], ((const float4*)(kr + 32))[1]);
            const float* vc = Vb + (size_t)(k0 + quad * 8) * DH + wave * 16 + l16;
#pragma unroll
            for (int j = 0; j < 8; ++j) {
                bv0[j] = (_Float16)vc[(size_t)j * DH];
                bv1[j] = (_Float16)vc[(size_t)(j + 32) * DH];
            }
        }

        // ---- dist/mask (touch-once stream: nontemporal) ----
        float dv[4]; int mv[4];
        if (quad < 2) {
            const int kc = k0 + wave * 16 + l16;
#pragma unroll
            for (int r = 0; r < 4; ++r) {
                const size_t idx = dm_base + (size_t)(quad * 4 + r) * SEQ + kc;
                dv[r] = __builtin_nontemporal_load(&distg[idx]);
                mv[r] = __builtin_nontemporal_load(&maskg[idx]);
            }
        }

        // ---- QK^T: wave w owns k-cols [k0+16w, +16) ----
        v4f accs = {0.f, 0.f, 0.f, 0.f};
        accs = __builtin_amdgcn_mfma_f32_16x16x32_f16(aq0, bk0, accs, 0, 0, 0);
        accs = __builtin_amdgcn_mfma_f32_16x16x32_f16(aq1, bk1, accs, 0, 0, 0);

        // ---- epilogue: scale, mask, exp; stash e (swizzled) + row-sum partials ----
        if (quad < 2) {
            const int kc = k0 + wave * 16 + l16;
#pragma unroll
            for (int r = 0; r < 4; ++r) {
                const int row = quad * 4 + r;
                const float sc = accs[r] * 0.125f * dv[r];
                const float e  = mv[r] ? 0.f : __expf(sc);
                rsum[r] += e;
                *(_Float16*)((char*)e_smem + (row * (SEQ * 2) + ((kc * 2) ^ (row << 4)))) = (_Float16)e;
            }
        }
        __syncthreads();   // e-tile visible to all waves (next iter writes disjoint cols)

        // ---- PV: A[m=l16][k]=e (swizzled b128, conflict-free), B from Vf planes ----
        v8h ap0 = {}, ap1 = {};
        if (l16 < TQ) {
            const int b0 = l16 * (SEQ * 2) + (((k0 + quad * 8) * 2) ^ (l16 << 4));
            const int b1 = l16 * (SEQ * 2) + (((k0 + 32 + quad * 8) * 2) ^ (l16 << 4));
            ap0 = *(const v8h*)((const char*)e_smem + b0);
            ap1 = *(const v8h*)((const char*)e_smem + b1);
        }
        acc_pv = __builtin_amdgcn_mfma_f32_16x16x32_f16(ap0, bv0, acc_pv, 0, 0, 0);
        acc_pv = __builtin_amdgcn_mfma_f32_16x16x32_f16(ap1, bv1, acc_pv, 0, 0, 0);
    }

    // ---- reduce row sums: sum over l16 within quad, then across waves ----
    if (quad < 2) {
#pragma unroll
        for (int r = 0; r < 4; ++r) {
            float v = rsum[r];
            v += __shfl_xor(v, 1);
            v += __shfl_xor(v, 2);
            v += __shfl_xor(v, 4);
            v += __shfl_xor(v, 8);
            if (l16 == 0) atomicAdd(&rs[quad * 4 + r], v);
        }
    }
    __syncthreads();

    // ---- context write ----
    if (quad < 2) {
#pragma unroll
        for (int r = 0; r < 4; ++r) {
            const int row = quad * 4 + r;
            const float inv = 1.f / rs[row];
            ctx_out[(bh_off + (size_t)(q0 + row)) * DH + wave * 16 + l16] = acc_pv[r] * inv;
        }
    }

    // ---- attn write: normalized e, nontemporal ext-vector stores ----
    {
        const int r  = tid >> 5;        // 0..7
        const int tt = tid & 31;        // 0..31
        const float invr = 1.f / rs[r];
        float* arow = attn_out + dm_base + (size_t)r * SEQ;
#pragma unroll
        for (int c = 0; c < 8; ++c) {
            const int col = c * 256 + tt * 8;
            const int b   = r * (SEQ * 2) + ((col * 2) ^ (r << 4));
            v8h e8 = *(const v8h*)((const char*)e_smem + b);
            v4f f0, f1;
            f0[0] = (float)e8[0] * invr; f0[1] = (float)e8[1] * invr;
            f0[2] = (float)e8[2] * invr; f0[3] = (float)e8[3] * invr;
            f1[0] = (float)e8[4] * invr; f1[1] = (float)e8[5] * invr;
            f1[2] = (float)e8[6] * invr; f1[3] = (float)e8[7] * invr;
            __builtin_nontemporal_store(f0, (v4f*)(arow + col));
            __builtin_nontemporal_store(f1, (v4f*)(arow + col) + 1);
        }
    }
}

extern "C" void kernel_launch(void* const* d_in, const int* in_sizes, int n_in,
                              void* d_out, int out_size, void* d_ws, size_t ws_size,
                              hipStream_t stream) {
    const float* Q    = (const float*)d_in[0];
    const float* K    = (const float*)d_in[1];
    const float* V    = (const float*)d_in[2];
    const float* dist = (const float*)d_in[3];
    const int*   mask = (const int*)d_in[4];

    float* ctx  = (float*)d_out;                                  // 4*8*2048*64
    float* attn = (float*)d_out + (size_t)4 * 8 * 2048 * 64;      // 4*8*2048*2048

    const size_t need = 4 * PLANE * sizeof(v8h);                  // 16 MiB
    if (d_ws != nullptr && ws_size >= need) {
        hipLaunchKernelGGL(prep_kernel, dim3(NKT, NBH), dim3(256), 0, stream,
                           K, V, (v8h*)d_ws);
        hipLaunchKernelGGL((dsda_kernel<true>), dim3(SEQ / TQ, NBH), dim3(256), 0, stream,
                           Q, K, V, dist, mask, (const v8h*)d_ws, ctx, attn);
    } else {
        hipLaunchKernelGGL((dsda_kernel<false>), dim3(SEQ / TQ, NBH), dim3(256), 0, stream,
                           Q, K, V, dist, mask, (const v8h*)nullptr, ctx, attn);
    }
}